// Round 5
// baseline (122.249 us; speedup 1.0000x reference)
//
#include <hip/hip_runtime.h>
#include <hip/hip_bf16.h>

// Problem constants (from reference setup_inputs)
#define T1 4095     // existing stack entries
#define TT 4096     // T1 + 1
#define B  64
#define M  128
#define BM (B * M)                // 8192
#define ROW4 (BM / 4)             // 2048 float4 per row
#define SCAN_THREADS 1024
#define EPT (TT / SCAN_THREADS)   // 4 elements per thread in scan
#define IPB 32                    // rows per fuse chunk
#define NCHUNK (TT / IPB)         // 128

typedef float f32x4 __attribute__((ext_vector_type(4)));

// Kernel 1: per batch b (one block per b):
//   sn[i] = relu(s[i] - relu(u - suffix_s[i])), sn[T1] = d
//   coeff[i] = min(sn[i], relu(1 - suffix_sn[i]))
// sn -> output layout [TT,B]; coeff -> TRANSPOSED [B,TT].
// Block 0 also re-arms the fuse kernel's atomic counters (every call).
__global__ __launch_bounds__(SCAN_THREADS) void scan_kernel(
    const float* __restrict__ s,    // [T1, B]
    const float* __restrict__ d,    // [B]
    const float* __restrict__ u,    // [B]
    float* __restrict__ sn_out,     // [TT, B]  (output 1)
    float* __restrict__ coeffT,     // [B, TT]  (workspace, transposed)
    unsigned int* __restrict__ counters) // [8*16]  (workspace)
{
    const int b = blockIdx.x;
    const int t = threadIdx.x;
    if (b == 0 && t < 8) counters[t * 16] = 0;   // 64B-spaced, re-armed each call
    __shared__ float sh[SCAN_THREADS];

    const int base = t * EPT;
    float sv[EPT];
    float sum = 0.f;
#pragma unroll
    for (int k = 0; k < EPT; ++k) {
        int i = base + k;
        float val = (i < T1) ? s[(size_t)i * B + b] : 0.f;
        sv[k] = val;
        sum += val;
    }
    const float mysum = sum;
    sh[t] = sum;
    __syncthreads();
#pragma unroll
    for (int dstep = 1; dstep < SCAN_THREADS; dstep <<= 1) {
        float add = (t + dstep < SCAN_THREADS) ? sh[t + dstep] : 0.f;
        __syncthreads();
        sh[t] += add;
        __syncthreads();
    }
    float suffix = sh[t] - mysum;   // sum over threads > t

    const float ub = u[b];
    float tot = suffix;
    float snv[EPT];
#pragma unroll
    for (int k = EPT - 1; k >= 0; --k) {
        float sval = sv[k];
        snv[k] = fmaxf(sval - fmaxf(ub - tot, 0.f), 0.f);
        tot += sval;
    }
    if (t == SCAN_THREADS - 1) snv[EPT - 1] = d[b];  // element T1: sn = d

    float sum2 = 0.f;
#pragma unroll
    for (int k = 0; k < EPT; ++k) sum2 += snv[k];
    __syncthreads();           // protect sh reuse
    sh[t] = sum2;
    __syncthreads();
#pragma unroll
    for (int dstep = 1; dstep < SCAN_THREADS; dstep <<= 1) {
        float add = (t + dstep < SCAN_THREADS) ? sh[t + dstep] : 0.f;
        __syncthreads();
        sh[t] += add;
        __syncthreads();
    }
    float suffix2 = sh[t] - sum2;

    float tot2 = suffix2;
    float cv[EPT];
#pragma unroll
    for (int k = EPT - 1; k >= 0; --k) {
        float snval = snv[k];
        cv[k] = fminf(snval, fmaxf(1.f - tot2, 0.f));
        tot2 += snval;
        sn_out[(size_t)(base + k) * B + b] = snval;
    }
    f32x4 cc = { cv[0], cv[1], cv[2], cv[3] };
    *(f32x4*)(coeffT + (size_t)b * TT + base) = cc;   // coalesced
}

// Kernel 2: fused Vn copy + coeff-weighted reduction, with last-block-done
// final reduce (no separate reduce kernel). Grid (8 bmTiles, 128 chunks) —
// the empirically-best round-2 strip layout.
__global__ __launch_bounds__(256) void fuse_kernel(
    const float* __restrict__ V,        // [T1, B, M]
    const float* __restrict__ v,        // [B, M]
    const float* __restrict__ coeffT,   // [B, TT]
    float* __restrict__ Vn,             // [TT, B, M] (output 0)
    float* __restrict__ partials,       // [NCHUNK, BM]
    unsigned int* __restrict__ counters,// [8*16]
    float* __restrict__ r)              // [B, M] (output 2)
{
    const int bmTile = blockIdx.x;                   // 0..7
    const int chunk  = blockIdx.y;                   // 0..127
    const int tid = threadIdx.x;
    const int bm4 = bmTile * 256 + tid;              // float4 column
    const int b = bm4 >> 5;                          // batch (M=128 -> 32 f4/batch)
    const int i0 = chunk * IPB;

    // Preload this thread's 32 coefficients (contiguous in coeffT).
    float c[IPB];
    const f32x4* cp = (const f32x4*)(coeffT + (size_t)b * TT + i0);
#pragma unroll
    for (int q = 0; q < IPB / 4; ++q) {
        f32x4 cc = cp[q];
        c[4*q+0] = cc.x; c[4*q+1] = cc.y; c[4*q+2] = cc.z; c[4*q+3] = cc.w;
    }

    f32x4 acc = {0.f, 0.f, 0.f, 0.f};
    const f32x4* Vp  = (const f32x4*)V;
    f32x4*       Vnp = (f32x4*)Vn;

    if (chunk != NCHUNK - 1) {
#pragma unroll 8
        for (int k = 0; k < IPB; ++k) {
            const size_t idx = (size_t)(i0 + k) * ROW4 + bm4;
            f32x4 val = __builtin_nontemporal_load(&Vp[idx]);
            __builtin_nontemporal_store(val, &Vnp[idx]);
            acc += c[k] * val;
        }
    } else {
#pragma unroll 8
        for (int k = 0; k < IPB - 1; ++k) {
            const size_t idx = (size_t)(i0 + k) * ROW4 + bm4;
            f32x4 val = __builtin_nontemporal_load(&Vp[idx]);
            __builtin_nontemporal_store(val, &Vnp[idx]);
            acc += c[k] * val;
        }
        f32x4 val = ((const f32x4*)v)[bm4];          // push v at i = T1
        __builtin_nontemporal_store(val, &Vnp[(size_t)T1 * ROW4 + bm4]);
        acc += c[IPB - 1] * val;
    }
    // Regular (cached) store so the tail reduce can hit L2.
    ((f32x4*)partials)[(size_t)chunk * ROW4 + bm4] = acc;

    // Last-block-done tail reduce for this bmTile strip.
    __shared__ int lastFlag;
    __syncthreads();                                  // drains vmem (waitcnt+barrier)
    if (tid == 0) {
        __threadfence();                              // release: publish partials
        unsigned int old = atomicAdd(&counters[bmTile * 16], 1u);
        lastFlag = (old == NCHUNK - 1);
    }
    __syncthreads();
    if (lastFlag) {
        __threadfence();                              // acquire: invalidate stale
        f32x4 racc = {0.f, 0.f, 0.f, 0.f};
#pragma unroll 8
        for (int cidx = 0; cidx < NCHUNK; ++cidx)     // fixed order -> deterministic
            racc += ((const f32x4*)partials)[(size_t)cidx * ROW4 + bm4];
        ((f32x4*)r)[bm4] = racc;
    }
}

extern "C" void kernel_launch(void* const* d_in, const int* in_sizes, int n_in,
                              void* d_out, int out_size, void* d_ws, size_t ws_size,
                              hipStream_t stream) {
    const float* V = (const float*)d_in[0];   // [T1,B,M]
    const float* s = (const float*)d_in[1];   // [T1,B,1]
    const float* d = (const float*)d_in[2];   // [B,1]
    const float* u = (const float*)d_in[3];   // [B,1]
    const float* v = (const float*)d_in[4];   // [B,M]

    float* out = (float*)d_out;
    float* Vn = out;                                   // TT*B*M
    float* sn = out + (size_t)TT * BM;                 // TT*B
    float* r  = sn + (size_t)TT * B;                   // B*M

    float* coeffT   = (float*)d_ws;                    // B*TT floats (1 MB)
    float* partials = coeffT + (size_t)B * TT;         // NCHUNK*BM floats (4 MB)
    unsigned int* counters = (unsigned int*)(partials + (size_t)NCHUNK * BM);

    scan_kernel<<<B, SCAN_THREADS, 0, stream>>>(s, d, u, sn, coeffT, counters);
    fuse_kernel<<<dim3(8, NCHUNK), 256, 0, stream>>>(V, v, coeffT, Vn, partials,
                                                     counters, r);
}

// Round 6
// 61.025 us; speedup vs baseline: 2.0033x; 2.0033x over previous
//
#include <hip/hip_runtime.h>
#include <hip/hip_bf16.h>

// Problem constants (from reference setup_inputs)
#define T1 4095     // existing stack entries
#define TT 4096     // T1 + 1
#define B  64
#define M  128
#define BM (B * M)                // 8192
#define ROW4 (BM / 4)             // 2048 float4 per row
#define SCAN_THREADS 256
#define EPT (TT / SCAN_THREADS)   // 16 elements per thread in scan
#define IPB 32                    // rows per fuse chunk
#define NCHUNK (TT / IPB)         // 128

typedef float f32x4 __attribute__((ext_vector_type(4)));

// Kernel 1: per batch b (one block per b):
//   sn[i] = relu(s[i] - relu(u - suffix_s[i])), sn[T1] = d
//   coeff[i] = min(sn[i], relu(1 - suffix_sn[i]))
// sn -> output layout [TT,B]; coeff -> TRANSPOSED [B,TT] for coalesced reuse.
// Suffix scans via wave shuffles (2 barriers total, vs 32 for Hillis-Steele).
__global__ __launch_bounds__(SCAN_THREADS) void scan_kernel(
    const float* __restrict__ s,    // [T1, B]
    const float* __restrict__ d,    // [B]
    const float* __restrict__ u,    // [B]
    float* __restrict__ sn_out,     // [TT, B]  (output 1)
    float* __restrict__ coeffT)     // [B, TT]  (workspace, transposed)
{
    const int b = blockIdx.x;
    const int t = threadIdx.x;
    const int lane = t & 63;
    const int wave = t >> 6;        // 0..3
    __shared__ float wtot1[4];
    __shared__ float wtot2[4];

    const int base = t * EPT;
    float sv[EPT];
    float sum = 0.f;
#pragma unroll
    for (int k = 0; k < EPT; ++k) {
        int i = base + k;
        float val = (i < T1) ? s[(size_t)i * B + b] : 0.f;
        sv[k] = val;
        sum += val;
    }

    // Wave-level inclusive suffix scan (Kogge-Stone on reversed order).
    float x = sum;
#pragma unroll
    for (int off = 1; off < 64; off <<= 1) {
        float y = __shfl_down(x, off);
        if (lane + off < 64) x += y;
    }
    if (lane == 0) wtot1[wave] = x;          // wave total (lane 0 = full sum)
    __syncthreads();
    float after = 0.f;
#pragma unroll
    for (int w = 0; w < 4; ++w)
        if (w > wave) after += wtot1[w];
    float suffix = after + x - sum;          // exclusive suffix for this thread

    const float ub = u[b];
    float tot = suffix;
    float snv[EPT];
#pragma unroll
    for (int k = EPT - 1; k >= 0; --k) {
        float sval = sv[k];
        snv[k] = fmaxf(sval - fmaxf(ub - tot, 0.f), 0.f);
        tot += sval;
    }
    if (t == SCAN_THREADS - 1) snv[EPT - 1] = d[b];  // element T1: sn = d

    float sum2 = 0.f;
#pragma unroll
    for (int k = 0; k < EPT; ++k) sum2 += snv[k];
    float x2 = sum2;
#pragma unroll
    for (int off = 1; off < 64; off <<= 1) {
        float y = __shfl_down(x2, off);
        if (lane + off < 64) x2 += y;
    }
    if (lane == 0) wtot2[wave] = x2;
    __syncthreads();
    float after2 = 0.f;
#pragma unroll
    for (int w = 0; w < 4; ++w)
        if (w > wave) after2 += wtot2[w];
    float suffix2 = after2 + x2 - sum2;

    float tot2 = suffix2;
    float cv[EPT];
#pragma unroll
    for (int k = EPT - 1; k >= 0; --k) {
        float snval = snv[k];
        cv[k] = fminf(snval, fmaxf(1.f - tot2, 0.f));
        tot2 += snval;
        sn_out[(size_t)(base + k) * B + b] = snval;
    }
    f32x4* cT4 = (f32x4*)(coeffT + (size_t)b * TT + base);
#pragma unroll
    for (int q = 0; q < EPT / 4; ++q) {
        f32x4 cc = { cv[4*q+0], cv[4*q+1], cv[4*q+2], cv[4*q+3] };
        cT4[q] = cc;
    }
}

// Kernel 2: fused Vn copy + coeff-weighted partial reduction.
// Round-2 strip layout (empirically best): grid (8 bmTiles, 128 chunks).
// Plain (cached) loads so L3 keeps V resident across replays; NT stores so
// Vn doesn't evict V from L3.
__global__ __launch_bounds__(256) void fuse_kernel(
    const float* __restrict__ V,        // [T1, B, M]
    const float* __restrict__ v,        // [B, M]
    const float* __restrict__ coeffT,   // [B, TT]
    float* __restrict__ Vn,             // [TT, B, M] (output 0)
    float* __restrict__ partials)       // [NCHUNK, BM]
{
    const int bmTile = blockIdx.x;                   // 0..7
    const int chunk  = blockIdx.y;                   // 0..127
    const int bm4 = bmTile * 256 + threadIdx.x;      // float4 column
    const int b = bm4 >> 5;                          // batch (32 f4 per batch)
    const int i0 = chunk * IPB;

    // Preload this thread's 32 coefficients (contiguous in coeffT).
    float c[IPB];
    const f32x4* cp = (const f32x4*)(coeffT + (size_t)b * TT + i0);
#pragma unroll
    for (int q = 0; q < IPB / 4; ++q) {
        f32x4 cc = cp[q];
        c[4*q+0] = cc.x; c[4*q+1] = cc.y; c[4*q+2] = cc.z; c[4*q+3] = cc.w;
    }

    f32x4 acc = {0.f, 0.f, 0.f, 0.f};
    const f32x4* Vp  = (const f32x4*)V;
    f32x4*       Vnp = (f32x4*)Vn;

    if (chunk != NCHUNK - 1) {
#pragma unroll 8
        for (int k = 0; k < IPB; ++k) {
            const size_t idx = (size_t)(i0 + k) * ROW4 + bm4;
            f32x4 val = Vp[idx];                       // cached read (L3 reuse)
            __builtin_nontemporal_store(val, &Vnp[idx]);
            acc += c[k] * val;
        }
    } else {
#pragma unroll 8
        for (int k = 0; k < IPB - 1; ++k) {
            const size_t idx = (size_t)(i0 + k) * ROW4 + bm4;
            f32x4 val = Vp[idx];
            __builtin_nontemporal_store(val, &Vnp[idx]);
            acc += c[k] * val;
        }
        f32x4 val = ((const f32x4*)v)[bm4];            // push v at i = T1
        __builtin_nontemporal_store(val, &Vnp[(size_t)T1 * ROW4 + bm4]);
        acc += c[IPB - 1] * val;
    }
    ((f32x4*)partials)[(size_t)chunk * ROW4 + bm4] = acc;
}

// Kernel 3: deterministic two-level reduction of partials -> r.
// 64 blocks x 256 threads; 8 chunk-groups x 32 float4 outputs per block.
__global__ __launch_bounds__(256) void reduce_kernel(
    const float* __restrict__ partials,  // [NCHUNK, BM]
    float* __restrict__ r)               // [B, M] (output 2)
{
    const int blk = blockIdx.x;          // 0..63
    const int tid = threadIdx.x;
    const int grp = tid >> 5;            // 0..7
    const int lane = tid & 31;
    const int out4 = blk * 32 + lane;    // float4 output index 0..2047

    f32x4 acc = {0.f, 0.f, 0.f, 0.f};
#pragma unroll 8
    for (int c = grp; c < NCHUNK; c += 8)
        acc += ((const f32x4*)partials)[(size_t)c * ROW4 + out4];

    __shared__ f32x4 sh[256];
    sh[tid] = acc;
    __syncthreads();
    if (tid < 128) sh[tid] += sh[tid + 128];
    __syncthreads();
    if (tid < 64) sh[tid] += sh[tid + 64];
    __syncthreads();
    if (tid < 32) {
        f32x4 res = sh[tid] + sh[tid + 32];
        ((f32x4*)r)[out4] = res;
    }
}

extern "C" void kernel_launch(void* const* d_in, const int* in_sizes, int n_in,
                              void* d_out, int out_size, void* d_ws, size_t ws_size,
                              hipStream_t stream) {
    const float* V = (const float*)d_in[0];   // [T1,B,M]
    const float* s = (const float*)d_in[1];   // [T1,B,1]
    const float* d = (const float*)d_in[2];   // [B,1]
    const float* u = (const float*)d_in[3];   // [B,1]
    const float* v = (const float*)d_in[4];   // [B,M]

    float* out = (float*)d_out;
    float* Vn = out;                                   // TT*B*M
    float* sn = out + (size_t)TT * BM;                 // TT*B
    float* r  = sn + (size_t)TT * B;                   // B*M

    float* coeffT   = (float*)d_ws;                    // B*TT floats (1 MB)
    float* partials = coeffT + (size_t)B * TT;         // NCHUNK*BM floats (4 MB)

    scan_kernel<<<B, SCAN_THREADS, 0, stream>>>(s, d, u, sn, coeffT);
    fuse_kernel<<<dim3(8, NCHUNK), 256, 0, stream>>>(V, v, coeffT, Vn, partials);
    reduce_kernel<<<64, 256, 0, stream>>>(partials, r);
}

// Round 7
// 60.844 us; speedup vs baseline: 2.0092x; 1.0030x over previous
//
#include <hip/hip_runtime.h>
#include <hip/hip_bf16.h>

// Problem constants (from reference setup_inputs)
#define T1 4095     // existing stack entries
#define TT 4096     // T1 + 1
#define B  64
#define M  128
#define BM (B * M)                // 8192
#define ROW4 (BM / 4)             // 2048 float4 per row
#define SCAN_THREADS 256
#define EPT (TT / SCAN_THREADS)   // 16 elements per thread in scan
#define IPB 32                    // rows per fuse chunk
#define HPB (IPB / 2)             // 16 rows per half-block
#define NCHUNK (TT / IPB)         // 128

typedef float f32x4 __attribute__((ext_vector_type(4)));

// Kernel 1: per batch b (one block per b):
//   sn[i] = relu(s[i] - relu(u - suffix_s[i])), sn[T1] = d
//   coeff[i] = min(sn[i], relu(1 - suffix_sn[i]))
// sn -> output layout [TT,B]; coeff -> TRANSPOSED [B,TT] for coalesced reuse.
__global__ __launch_bounds__(SCAN_THREADS) void scan_kernel(
    const float* __restrict__ s,    // [T1, B]
    const float* __restrict__ d,    // [B]
    const float* __restrict__ u,    // [B]
    float* __restrict__ sn_out,     // [TT, B]  (output 1)
    float* __restrict__ coeffT)     // [B, TT]  (workspace, transposed)
{
    const int b = blockIdx.x;
    const int t = threadIdx.x;
    const int lane = t & 63;
    const int wave = t >> 6;        // 0..3
    __shared__ float wtot1[4];
    __shared__ float wtot2[4];

    const int base = t * EPT;
    float sv[EPT];
    float sum = 0.f;
#pragma unroll
    for (int k = 0; k < EPT; ++k) {
        int i = base + k;
        float val = (i < T1) ? s[(size_t)i * B + b] : 0.f;
        sv[k] = val;
        sum += val;
    }

    // Wave-level inclusive suffix scan (Kogge-Stone, high-to-low).
    float x = sum;
#pragma unroll
    for (int off = 1; off < 64; off <<= 1) {
        float y = __shfl_down(x, off);
        if (lane + off < 64) x += y;
    }
    if (lane == 0) wtot1[wave] = x;          // wave total
    __syncthreads();
    float after = 0.f;
#pragma unroll
    for (int w = 0; w < 4; ++w)
        if (w > wave) after += wtot1[w];
    float suffix = after + x - sum;          // exclusive suffix for this thread

    const float ub = u[b];
    float tot = suffix;
    float snv[EPT];
#pragma unroll
    for (int k = EPT - 1; k >= 0; --k) {
        float sval = sv[k];
        snv[k] = fmaxf(sval - fmaxf(ub - tot, 0.f), 0.f);
        tot += sval;
    }
    if (t == SCAN_THREADS - 1) snv[EPT - 1] = d[b];  // element T1: sn = d

    float sum2 = 0.f;
#pragma unroll
    for (int k = 0; k < EPT; ++k) sum2 += snv[k];
    float x2 = sum2;
#pragma unroll
    for (int off = 1; off < 64; off <<= 1) {
        float y = __shfl_down(x2, off);
        if (lane + off < 64) x2 += y;
    }
    if (lane == 0) wtot2[wave] = x2;
    __syncthreads();
    float after2 = 0.f;
#pragma unroll
    for (int w = 0; w < 4; ++w)
        if (w > wave) after2 += wtot2[w];
    float suffix2 = after2 + x2 - sum2;

    float tot2 = suffix2;
    float cv[EPT];
#pragma unroll
    for (int k = EPT - 1; k >= 0; --k) {
        float snval = snv[k];
        cv[k] = fminf(snval, fmaxf(1.f - tot2, 0.f));
        tot2 += snval;
        sn_out[(size_t)(base + k) * B + b] = snval;
    }
    f32x4* cT4 = (f32x4*)(coeffT + (size_t)b * TT + base);
#pragma unroll
    for (int q = 0; q < EPT / 4; ++q) {
        f32x4 cc = { cv[4*q+0], cv[4*q+1], cv[4*q+2], cv[4*q+3] };
        cT4[q] = cc;
    }
}

// Kernel 2: fused Vn copy + coeff-weighted partial reduction.
// Strip layout (empirically best), now 512-thread blocks for 32 waves/CU:
// grid (8 bmTiles, 128 chunks); half-block 0 does rows [i0, i0+16),
// half-block 1 does [i0+16, i0+32); halves combined via LDS.
// Cached V loads (L3 keeps V resident across replays); NT stores for Vn.
__global__ __launch_bounds__(512) void fuse_kernel(
    const float* __restrict__ V,        // [T1, B, M]
    const float* __restrict__ v,        // [B, M]
    const float* __restrict__ coeffT,   // [B, TT]
    float* __restrict__ Vn,             // [TT, B, M] (output 0)
    float* __restrict__ partials)       // [NCHUNK, BM]
{
    const int bmTile = blockIdx.x;                   // 0..7
    const int chunk  = blockIdx.y;                   // 0..127
    const int tid  = threadIdx.x;                    // 0..511
    const int half = tid >> 8;                       // 0 or 1
    const int t    = tid & 255;
    const int bm4  = bmTile * 256 + t;               // float4 column
    const int b    = bm4 >> 5;                       // batch (32 f4 per batch)
    const int i0   = chunk * IPB + half * HPB;       // 16 rows per half

    // Preload this half's 16 coefficients (contiguous in coeffT).
    float c[HPB];
    const f32x4* cp = (const f32x4*)(coeffT + (size_t)b * TT + i0);
#pragma unroll
    for (int q = 0; q < HPB / 4; ++q) {
        f32x4 cc = cp[q];
        c[4*q+0] = cc.x; c[4*q+1] = cc.y; c[4*q+2] = cc.z; c[4*q+3] = cc.w;
    }

    f32x4 acc = {0.f, 0.f, 0.f, 0.f};
    const f32x4* Vp  = (const f32x4*)V;
    f32x4*       Vnp = (f32x4*)Vn;

    const bool lastHalf = (chunk == NCHUNK - 1) && (half == 1);
    if (!lastHalf) {
#pragma unroll
        for (int k = 0; k < HPB; ++k) {
            const size_t idx = (size_t)(i0 + k) * ROW4 + bm4;
            f32x4 val = Vp[idx];                       // cached read (L3 reuse)
            __builtin_nontemporal_store(val, &Vnp[idx]);
            acc += c[k] * val;
        }
    } else {
#pragma unroll
        for (int k = 0; k < HPB - 1; ++k) {
            const size_t idx = (size_t)(i0 + k) * ROW4 + bm4;
            f32x4 val = Vp[idx];
            __builtin_nontemporal_store(val, &Vnp[idx]);
            acc += c[k] * val;
        }
        f32x4 val = ((const f32x4*)v)[bm4];            // push v at i = T1
        __builtin_nontemporal_store(val, &Vnp[(size_t)T1 * ROW4 + bm4]);
        acc += c[HPB - 1] * val;
    }

    // Combine the two halves (4 KB LDS, one barrier), then store partial.
    __shared__ f32x4 sh[256];
    if (half == 1) sh[t] = acc;
    __syncthreads();
    if (half == 0)
        ((f32x4*)partials)[(size_t)chunk * ROW4 + bm4] = acc + sh[t];
}

// Kernel 3: deterministic two-level reduction of partials -> r.
// 64 blocks x 256 threads; 8 chunk-groups x 32 float4 outputs per block.
__global__ __launch_bounds__(256) void reduce_kernel(
    const float* __restrict__ partials,  // [NCHUNK, BM]
    float* __restrict__ r)               // [B, M] (output 2)
{
    const int blk = blockIdx.x;          // 0..63
    const int tid = threadIdx.x;
    const int grp = tid >> 5;            // 0..7
    const int lane = tid & 31;
    const int out4 = blk * 32 + lane;    // float4 output index 0..2047

    f32x4 acc = {0.f, 0.f, 0.f, 0.f};
#pragma unroll 8
    for (int c = grp; c < NCHUNK; c += 8)
        acc += ((const f32x4*)partials)[(size_t)c * ROW4 + out4];

    __shared__ f32x4 sh[256];
    sh[tid] = acc;
    __syncthreads();
    if (tid < 128) sh[tid] += sh[tid + 128];
    __syncthreads();
    if (tid < 64) sh[tid] += sh[tid + 64];
    __syncthreads();
    if (tid < 32) {
        f32x4 res = sh[tid] + sh[tid + 32];
        ((f32x4*)r)[out4] = res;
    }
}

extern "C" void kernel_launch(void* const* d_in, const int* in_sizes, int n_in,
                              void* d_out, int out_size, void* d_ws, size_t ws_size,
                              hipStream_t stream) {
    const float* V = (const float*)d_in[0];   // [T1,B,M]
    const float* s = (const float*)d_in[1];   // [T1,B,1]
    const float* d = (const float*)d_in[2];   // [B,1]
    const float* u = (const float*)d_in[3];   // [B,1]
    const float* v = (const float*)d_in[4];   // [B,M]

    float* out = (float*)d_out;
    float* Vn = out;                                   // TT*B*M
    float* sn = out + (size_t)TT * BM;                 // TT*B
    float* r  = sn + (size_t)TT * B;                   // B*M

    float* coeffT   = (float*)d_ws;                    // B*TT floats (1 MB)
    float* partials = coeffT + (size_t)B * TT;         // NCHUNK*BM floats (4 MB)

    scan_kernel<<<B, SCAN_THREADS, 0, stream>>>(s, d, u, sn, coeffT);
    fuse_kernel<<<dim3(8, NCHUNK), 512, 0, stream>>>(V, v, coeffT, Vn, partials);
    reduce_kernel<<<64, 256, 0, stream>>>(partials, r);
}